// Round 10
// baseline (364.986 us; speedup 1.0000x reference)
//
#include <hip/hip_runtime.h>
#include <hip/hip_bf16.h>

// ---------------------------------------------------------------------------
// TokenDiscrepancyLoss: loss = 0.1 * sum_{mask} [ (||t||^2 + sum_c p_c (||c||^2 - 2 t.c)) / H ]
// with p = softmax(hs @ W + b) over C=8192.
//
// R16: k_dual regeometried to BM=256 x BN=128, 512 thr (8 waves of 64x64 —
// per-wave fragment/acc/ctp math byte-identical to R13, so dual-phase in
// registers still fits: acc 64 + ctp 32 VGPR). Staged bytes 0.75x
// (MNK(1/BM+1/BN)); LDS 3 x 24KB = 72KB -> 2 blocks x 8 waves = 16
// waves/CU (vs 12); per-CU sequential batches 3 -> 2. Same counted-vmcnt
// 2-deep pipeline (3 loads/stage/wave -> vmcnt(6)). Epilogue pm/pl/ps now
// repacked via LDS -> coalesced 1KB-run agent stores (R15's scalar agent
// stores caused 2x write-through amplification, WRITE 25.4 MB). Fused
// fence-free merge tail kept (saves ~21 us of dispatch cost, R14/R15).
// Dispatches: memset, k_compact, k_prep_all, k_dual (4 total).
// ---------------------------------------------------------------------------

#define H        1024
#define CBN      8192
#define NTOK     8192
#define MT       128              // prep slab panel rows
#define BM       256              // GEMM tile M (2 slab panels)
#define NKC      16               // H / 64 kc-chunks per phase
#define NSTG     32               // unified stages = 2 * NKC
#define NCHK     128              // partial strips (one per 64-col wave tile)
#define LOSSW    0.1f
#define CTC      1024.0f          // centering for bf16 ct registers
#define WSCALE   16.0f            // W pre-scale (pow2) for fp8 range
#define SB_UNIT  127              // e8m0 scale = 2^0
#define SB_W     123              // e8m0 scale = 2^-4 (undoes WSCALE)
#define SLAB     131072           // bytes per 128-row panel: 16kc*8KB

typedef __attribute__((ext_vector_type(4)))  int   i32x4;
typedef __attribute__((ext_vector_type(8)))  int   i32x8;
typedef __attribute__((ext_vector_type(16))) float f32x16;

__device__ __forceinline__ unsigned short f2bf(float f) {
  union { float f; unsigned u; } x; x.f = f;
  return (unsigned short)((x.u + 0x7FFFu + ((x.u >> 16) & 1u)) >> 16); // RNE
}
__device__ __forceinline__ float bf2f(unsigned short u) {
  union { unsigned u; float f; } x; x.u = (unsigned)u << 16;
  return x.f;
}

// ---- fp32 -> fp8 e4m3fn (OCP) ----
__device__ unsigned char f2fp8_sw(float f) {
  float a = fabsf(f);
  unsigned s = f < 0.f ? 0x80u : 0u;
  if (!(a < 448.f)) return (unsigned char)(s | 0x7Eu);
  if (a < 0.0009765625f) return (unsigned char)s;
  int e; float m = frexpf(a, &e);
  int te = e - 1;
  if (te < -6) {
    int q = (int)rintf(a * 512.f); if (q > 7) q = 7;
    return (unsigned char)(s | q);
  }
  int q = (int)rintf((2.f * m - 1.f) * 8.f);
  int E = te + 7, M = q;
  if (q == 8) { E += 1; M = 0; }
  if (E > 15) return (unsigned char)(s | 0x7Eu);
  return (unsigned char)(s | (E << 3) | M);
}
__device__ __forceinline__ unsigned pack4(float a, float b, float c, float d) {
#if __has_builtin(__builtin_amdgcn_cvt_pk_fp8_f32)
  int r = __builtin_amdgcn_cvt_pk_fp8_f32(a, b, 0, false);
  r     = __builtin_amdgcn_cvt_pk_fp8_f32(c, d, r, true);
  return (unsigned)r;
#else
  return (unsigned)f2fp8_sw(a) | ((unsigned)f2fp8_sw(b) << 8) |
         ((unsigned)f2fp8_sw(c) << 16) | ((unsigned)f2fp8_sw(d) << 24);
#endif
}

// kc-chunk internal offset for (row c, local k octet g in [0,8)):
//   half = g>>2 (k>>5), b4 = (g>>1)&1 ((k>>4)&1), lo8 = (g&1)*8 (k&8)
__device__ __forceinline__ int slab_off(int g, int c) {
  return ((g >> 2) << 12) + (((g >> 1) & 1) << 11) + (c << 4) + ((g & 1) << 3);
}

// async global->LDS DMA, 16B/lane; LDS dest = wave-uniform base + lane*16
__device__ __forceinline__ void load_lds16(const void* g, void* l) {
  __builtin_amdgcn_global_load_lds((const __attribute__((address_space(1))) void*)g,
                                   (__attribute__((address_space(3))) void*)l,
                                   16, 0, 0);
}
__device__ __forceinline__ void wait_vm6() { asm volatile("s_waitcnt vmcnt(6)" ::: "memory"); }
__device__ __forceinline__ void wait_vm3() { asm volatile("s_waitcnt vmcnt(3)" ::: "memory"); }
__device__ __forceinline__ void wait_vm0() { asm volatile("s_waitcnt vmcnt(0)" ::: "memory"); }
__device__ __forceinline__ void barrier_raw() { asm volatile("s_barrier" ::: "memory"); }

// XCD-aware tile mapping for the 32x64 grid (tilex 0..31, tiley 0..63)
__device__ __forceinline__ void tile_map(int* tilex, int* tiley) {
  const int flat = blockIdx.y * 32 + blockIdx.x;
  const int xcd = flat & 7, loc = flat >> 3;
  *tiley = xcd * 8 + (loc & 7);
  *tilex = loc >> 3;
}

// ---------------- k_compact: image-token mask -> compacted index list ------
__global__ __launch_bounds__(256) void k_compact(
    const int* __restrict__ ids, int* __restrict__ list,
    int* __restrict__ counter) {
  const int b = blockIdx.x, t = threadIdx.x;
  int f = 0;
  #pragma unroll
  for (int j = 0; j < 16; ++j) f |= ids[2 * (t * 16 + j) + 1];
  int anyodd = __syncthreads_or(f);
  int i = b * 256 + t;
  int v = anyodd ? ids[i] : ids[2 * i];
  bool act = (v == 1);
  unsigned long long mask = __ballot(act);
  int lane = t & 63;
  int base = 0;
  if (lane == 0) base = atomicAdd(counter, __popcll(mask));
  base = __shfl(base, 0);
  if (act) list[base + __popcll(mask & ((1ull << lane) - 1ull))] = i;
}

// -------- k_prep_all: 4096 balanced chunk blocks -> fp8 slabs + csq/tsq ----
__global__ __launch_bounds__(256) void k_prep_all(
    const float* __restrict__ hs, const float* __restrict__ tg,
    const float* __restrict__ cb, const float* __restrict__ W,
    const int* __restrict__ list, const int* __restrict__ counter,
    float* __restrict__ csq, float* __restrict__ tsq,
    unsigned char* __restrict__ Wtb, unsigned char* __restrict__ Cbb,
    unsigned char* __restrict__ Ahs, unsigned char* __restrict__ Atg) {
  __shared__ __align__(16) unsigned char tile[8192];
  __shared__ int stok[128];
  const int b = blockIdx.x, t = threadIdx.x;

  if (b < 1024) {
    // W [H][C] fp32 -> fp8 slab [tiley][kc][half][b4][c][16], scaled x16
    const int tiley = b >> 4, kc = b & 15;
    const int c = t & 127, gh = t >> 7;
    unsigned char* dst = Wtb + (size_t)tiley * SLAB + (size_t)kc * 8192;
    #pragma unroll
    for (int gi = 0; gi < 4; ++gi) {
      const int g = gh * 4 + gi;
      const float* wp = W + (size_t)(kc * 64 + g * 8) * CBN + tiley * 128 + c;
      float v[8];
      #pragma unroll
      for (int j = 0; j < 8; ++j) v[j] = wp[(size_t)j * CBN] * WSCALE;
      uint2 pk;
      pk.x = pack4(v[0], v[1], v[2], v[3]);
      pk.y = pack4(v[4], v[5], v[6], v[7]);
      *(uint2*)(dst + slab_off(g, c)) = pk;
    }
    return;
  }

  const int sub = t >> 4, kq = t & 15;
  const int g = kq >> 1;
  const int toff = ((g >> 2) << 12) + (((g >> 1) & 1) << 11) + ((g & 1) << 3)
                 + ((kq & 1) << 2);

  if (b < 2048) {
    // codebook [C][H] fp32 -> fp8 chunk + csq partials
    const int idx = b - 1024, tiley = idx >> 4, kc = idx & 15;
    #pragma unroll
    for (int rr = 0; rr < 8; ++rr) {
      const int c = rr * 16 + sub;
      const float4 v = *(const float4*)(cb + (size_t)(tiley * 128 + c) * H
                                        + kc * 64 + kq * 4);
      float sq = v.x * v.x + v.y * v.y + v.z * v.z + v.w * v.w;
      sq += __shfl_xor(sq, 1); sq += __shfl_xor(sq, 2);
      sq += __shfl_xor(sq, 4); sq += __shfl_xor(sq, 8);
      if (kq == 0) atomicAdd(&csq[tiley * 128 + c], sq);
      *(unsigned*)&tile[toff + c * 16] = pack4(v.x, v.y, v.z, v.w);
    }
    __syncthreads();
    const uint4* tp = (const uint4*)tile;
    uint4 x0 = tp[t * 2], x1 = tp[t * 2 + 1];
    unsigned char* dst = Cbb + (size_t)tiley * SLAB + (size_t)kc * 8192 + t * 32;
    *(uint4*)dst = x0; *(uint4*)(dst + 16) = x1;
    return;
  }

  // gathered token chunks (hs or tg)
  const bool is_tg = (b >= 3072);
  const int idx = (b - 2048) & 1023, tilex = idx >> 4, kc = idx & 15;
  const int n = *counter;
  const int n_pad = (n + MT - 1) & ~(MT - 1);
  if (tilex * MT >= n_pad) return;
  if (t < 128) {
    int ga = tilex * MT + t;
    stok[t] = list[(ga < n) ? ga : 0];
  }
  __syncthreads();
  const float* src = is_tg ? tg : hs;
  #pragma unroll
  for (int rr = 0; rr < 8; ++rr) {
    const int c = rr * 16 + sub;
    const float4 v = *(const float4*)(src + (size_t)stok[c] * H
                                      + kc * 64 + kq * 4);
    if (is_tg) {
      float sq = v.x * v.x + v.y * v.y + v.z * v.z + v.w * v.w;
      sq += __shfl_xor(sq, 1); sq += __shfl_xor(sq, 2);
      sq += __shfl_xor(sq, 4); sq += __shfl_xor(sq, 8);
      if (kq == 0) atomicAdd(&tsq[tilex * MT + c], sq);
    }
    *(unsigned*)&tile[toff + c * 16] = pack4(v.x, v.y, v.z, v.w);
  }
  __syncthreads();
  const uint4* tp = (const uint4*)tile;
  uint4 x0 = tp[t * 2], x1 = tp[t * 2 + 1];
  unsigned char* dst = (is_tg ? Atg : Ahs)
                     + (size_t)tilex * SLAB + (size_t)kc * 8192 + t * 32;
  *(uint4*)dst = x0; *(uint4*)(dst + 16) = x1;
}

// ---------- dual-phase GEMM, BM=256 x BN=128, 512 thr, counted vmcnt -------
// 8 waves as 4(row) x 2(col); wave tile 64x64 (fragment math = R13).
// Stage s < 16: phase 1 (Atg x Cbb, 2^0); s >= 16: phase 2 (Ahs x Wtb, 2^-4).
// Per stage: A = 2 slab panels (16 KB) + B = 1 panel (8 KB); wave w loads
// A granules {w (panel0), w (panel1)} + B granule {w} = 3 loads -> vmcnt(6)
// keeps 2 stages in flight. 3 buffers x 24 KB = 72 KB -> 2 blocks/CU,
// 16 waves/CU. Epilogue: LDS repack -> coalesced agent stores. Fused
// fence-free merge tail (tdone[tilex] to 64; merger reads agent loads).
__global__ __launch_bounds__(512, 2) void k_dual(
    const unsigned char* __restrict__ Atg, const unsigned char* __restrict__ Cbb,
    const unsigned char* __restrict__ Ahs, const unsigned char* __restrict__ Wtb,
    const float* __restrict__ csq, const float* __restrict__ bias,
    const int* __restrict__ counter, const float* __restrict__ tsq,
    float* __restrict__ pm, float* __restrict__ pl, float* __restrict__ ps,
    int* __restrict__ tdone, int* __restrict__ done2,
    float* __restrict__ lsum, float* __restrict__ out) {
  const int n = *counter;
  int tilex, tiley;
  tile_map(&tilex, &tiley);
  if (tilex * BM >= n) return;

  __shared__ __align__(16) unsigned char sA[3][16384];
  __shared__ __align__(16) unsigned char sB[3][8192];
  __shared__ int s_done;

  const int t = threadIdx.x;
  const int w = t >> 6, lane = t & 63;
  const int wr = w >> 1, wc = w & 1;
  const int hi32 = lane >> 5, lc32 = lane & 31;
  const int rb = (hi32 << 12) + (lc32 << 4);     // half*4096 + row_lane*16
  const size_t Aoff0 = (size_t)(2 * tilex) * SLAB;
  const size_t Aoff1 = Aoff0 + SLAB;
  const size_t Boff  = (size_t)tiley * SLAB;

  // csq prefetch (consumed at the s==16 ctp pack)
  float cqc[2];
  #pragma unroll
  for (int ni = 0; ni < 2; ++ni)
    cqc[ni] = csq[tiley * 128 + wc * 64 + ni * 32 + lc32] - CTC;

  const f32x16 fz = {0.f, 0.f, 0.f, 0.f, 0.f, 0.f, 0.f, 0.f,
                     0.f, 0.f, 0.f, 0.f, 0.f, 0.f, 0.f, 0.f};
  f32x16 acc[2][2];
  #pragma unroll
  for (int mi = 0; mi < 2; ++mi)
    #pragma unroll
    for (int ni = 0; ni < 2; ++ni) acc[mi][ni] = fz;
  unsigned ctp[2][2][8];

// issue stage ss into buffer nb: wave w -> A panel0 granule w, A panel1
// granule w (at +8192), B granule w. 3 x 1 KB wave-loads.
#define ISSUE_S(ss, nb)                                                      \
  do {                                                                       \
    const unsigned char* asrc = ((ss) < NKC ? Atg : Ahs);                    \
    const unsigned char* bsrc = ((ss) < NKC ? Cbb : Wtb);                    \
    const size_t ko = (size_t)((ss) & 15) * 8192 + (size_t)lane * 16         \
                    + (size_t)w * 1024;                                      \
    load_lds16(asrc + Aoff0 + ko, &sA[nb][w * 1024]);                        \
    load_lds16(asrc + Aoff1 + ko, &sA[nb][8192 + w * 1024]);                 \
    load_lds16(bsrc + Boff  + ko, &sB[nb][w * 1024]);                        \
  } while (0)

  ISSUE_S(0, 0);
  ISSUE_S(1, 1);
  int cur = 0;
  #pragma unroll 1
  for (int s = 0; s < NSTG; ++s) {
    const int left = NSTG - 1 - s;
    if (left >= 2) {
      const int nb = (cur + 2 >= 3) ? cur - 1 : cur + 2;
      ISSUE_S(s + 2, nb);
      wait_vm6();                      // stage s landed; s+1, s+2 in flight
    } else if (left == 1) {
      wait_vm3();
    } else {
      wait_vm0();
    }
    barrier_raw();

    if (s == NKC) {
      // phase boundary: pack ct = cqc - 2*cross into bf16 pairs, reset acc
      #pragma unroll
      for (int mi = 0; mi < 2; ++mi)
        #pragma unroll
        for (int ni = 0; ni < 2; ++ni) {
          #pragma unroll
          for (int rp = 0; rp < 8; ++rp) {
            const float v0 = cqc[ni] - 2.f * acc[mi][ni][2 * rp];
            const float v1 = cqc[ni] - 2.f * acc[mi][ni][2 * rp + 1];
            ctp[mi][ni][rp] = (unsigned)f2bf(v0) | ((unsigned)f2bf(v1) << 16);
          }
          acc[mi][ni] = fz;
        }
    }

    {
      const int sb = (s < NKC) ? SB_UNIT : SB_W;
      i32x8 aF[2], bF[2];
      #pragma unroll
      for (int mi = 0; mi < 2; ++mi) {
        const int gm = wr * 64 + mi * 32;              // 0..255
        const unsigned char* ap = &sA[cur][(gm >> 7) * 8192
                                           + ((gm & 127) << 4) + rb];
        i32x4 lo = *(const i32x4*)(ap);
        i32x4 hh = *(const i32x4*)(ap + 2048);
        aF[mi] = __builtin_shufflevector(lo, hh, 0, 1, 2, 3, 4, 5, 6, 7);
      }
      #pragma unroll
      for (int ni = 0; ni < 2; ++ni) {
        const int gn = wc * 64 + ni * 32;              // 0..127
        const unsigned char* bp = &sB[cur][(gn << 4) + rb];
        i32x4 lo = *(const i32x4*)(bp);
        i32x4 hh = *(const i32x4*)(bp + 2048);
        bF[ni] = __builtin_shufflevector(lo, hh, 0, 1, 2, 3, 4, 5, 6, 7);
      }
      #pragma unroll
      for (int mi = 0; mi < 2; ++mi)
        #pragma unroll
        for (int ni = 0; ni < 2; ++ni)
          acc[mi][ni] = __builtin_amdgcn_mfma_scale_f32_32x32x64_f8f6f4(
              aF[mi], bF[ni], acc[mi][ni], 0, 0, 0, SB_UNIT, 0, sb);
    }
    barrier_raw();
    cur = (cur + 1 >= 3) ? 0 : cur + 1;
  }
#undef ISSUE_S

  // ------- fused softmax epilogue: compute -> LDS repack (3 KB/chunk) ------
  float bv[2];
  #pragma unroll
  for (int ni = 0; ni < 2; ++ni)
    bv[ni] = bias[tiley * 128 + wc * 64 + ni * 32 + lc32];

  float* sp = (float*)&sA[0][0];        // [3][2][256]: pm, pl, ps
  #pragma unroll
  for (int mi = 0; mi < 2; ++mi) {
    #pragma unroll
    for (int r = 0; r < 16; ++r) {
      float lg[2], ct[2];
      #pragma unroll
      for (int ni = 0; ni < 2; ++ni) {
        lg[ni] = acc[mi][ni][r] + bv[ni];
        ct[ni] = bf2f((unsigned short)((ctp[mi][ni][r >> 1] >> ((r & 1) * 16)) & 0xFFFFu));
      }
      float tmax = fmaxf(lg[0], lg[1]);
      #pragma unroll
      for (int d = 1; d < 32; d <<= 1) tmax = fmaxf(tmax, __shfl_xor(tmax, d));
      float le = 0.f, se = 0.f;
      #pragma unroll
      for (int ni = 0; ni < 2; ++ni) {
        const float e = __expf(lg[ni] - tmax);
        le += e; se += e * ct[ni];
      }
      #pragma unroll
      for (int d = 1; d < 32; d <<= 1) {
        le += __shfl_xor(le, d);
        se += __shfl_xor(se, d);
      }
      if (lc32 == 0) {
        // 32x32 C/D: local row = wr*64 + mi*32 + 4*hi32 + (r&3) + 8*(r>>2)
        const int rl = wr * 64 + mi * 32 + 4 * hi32 + (r & 3) + 8 * (r >> 2);
        sp[wc * 256 + rl]        = tmax;
        sp[512 + wc * 256 + rl]  = le;
        sp[1024 + wc * 256 + rl] = se;
      }
    }
  }
  __syncthreads();

  // coalesced agent stores: 1 KB contiguous run per (array, chunk)
  {
    const int cl = t >> 8, rl = t & 255;               // chunk-local, row
    const int chunk = tiley * 2 + cl;
    const int row = tilex * BM + rl;
    __hip_atomic_store(&pm[(size_t)chunk * NTOK + row], sp[cl * 256 + rl],
                       __ATOMIC_RELAXED, __HIP_MEMORY_SCOPE_AGENT);
    __hip_atomic_store(&pl[(size_t)chunk * NTOK + row], sp[512 + cl * 256 + rl],
                       __ATOMIC_RELAXED, __HIP_MEMORY_SCOPE_AGENT);
    __hip_atomic_store(&ps[(size_t)chunk * NTOK + row], sp[1024 + cl * 256 + rl],
                       __ATOMIC_RELAXED, __HIP_MEMORY_SCOPE_AGENT);
  }

  // ---------------- fence-free merge tail (last col-block per tilex) -------
  wait_vm0();                           // this wave's agent stores completed
  __syncthreads();                      // => all waves' stores completed
  if (t == 0)
    s_done = __hip_atomic_fetch_add(&tdone[tilex], 1,
                                    __ATOMIC_RELAXED, __HIP_MEMORY_SCOPE_AGENT);
  __syncthreads();
  if (s_done != 63) return;

  const int tl = t & 255, hf = t >> 8;
  const int row = tilex * BM + tl;
  float M = -1e30f, L = 0.f, S = 0.f;
  for (int j2 = hf * 64; j2 < hf * 64 + 64; ++j2)
    M = fmaxf(M, __hip_atomic_load(&pm[(size_t)j2 * NTOK + row],
                                   __ATOMIC_RELAXED, __HIP_MEMORY_SCOPE_AGENT));
  for (int j2 = hf * 64; j2 < hf * 64 + 64; ++j2) {
    const float mv = __hip_atomic_load(&pm[(size_t)j2 * NTOK + row],
                                       __ATOMIC_RELAXED, __HIP_MEMORY_SCOPE_AGENT);
    const float lv = __hip_atomic_load(&pl[(size_t)j2 * NTOK + row],
                                       __ATOMIC_RELAXED, __HIP_MEMORY_SCOPE_AGENT);
    const float sv = __hip_atomic_load(&ps[(size_t)j2 * NTOK + row],
                                       __ATOMIC_RELAXED, __HIP_MEMORY_SCOPE_AGENT);
    const float e = __expf(mv - M);
    L += lv * e;
    S += sv * e;
  }
  sp[hf * 256 + tl]        = M;
  sp[512 + hf * 256 + tl]  = L;
  sp[1024 + hf * 256 + tl] = S;
  __syncthreads();
  if (hf == 0) {
    const float M1 = sp[256 + tl];
    const float L1 = sp[512 + 256 + tl];
    const float S1 = sp[1024 + 256 + tl];
    const float Mm = fmaxf(M, M1);
    const float e0 = __expf(M - Mm), e1 = __expf(M1 - Mm);
    const float Lt = L * e0 + L1 * e1, St = S * e0 + S1 * e1;
    float val = (row < n) ? (tsq[row] + CTC + St / Lt) * (LOSSW / (float)H)
                          : 0.f;
    #pragma unroll
    for (int d = 1; d < 64; d <<= 1) val += __shfl_xor(val, d);
    if ((tl & 63) == 0) atomicAdd(lsum, val);
  }
  __syncthreads();
  if (t == 0) {
    const int ntx = (n + BM - 1) >> 8;
    const int k2 = __hip_atomic_fetch_add(done2, 1,
                                          __ATOMIC_RELAXED, __HIP_MEMORY_SCOPE_AGENT);
    if (k2 == ntx - 1) {
      out[0] = atomicAdd(lsum, 0.0f);   // atomic read-back = final sum
    }
  }
}

// ---------------------------------------------------------------------------
extern "C" void kernel_launch(void* const* d_in, const int* in_sizes, int n_in,
                              void* d_out, int out_size, void* d_ws, size_t ws_size,
                              hipStream_t stream) {
  const float* hs   = (const float*)d_in[0];
  const int*   ids  = (const int*)d_in[1];
  const float* tg   = (const float*)d_in[2];
  const float* cb   = (const float*)d_in[3];
  const float* W    = (const float*)d_in[4];
  const float* bias = (const float*)d_in[5];

  char* ws = (char*)d_ws;
  constexpr size_t OFF_CSQ  = 0;                       // f32[8192] (zeroed)
  constexpr size_t OFF_TSQ  = 32768;                   // f32[8192] (zeroed)
  constexpr size_t OFF_CNT  = 65536;                   // int (zeroed)
  constexpr size_t OFF_DONE = 65540;                   // int (zeroed)
  constexpr size_t OFF_LSUM = 65544;                   // f32 (zeroed)
  constexpr size_t OFF_TDN  = 65548;                   // int[64] (zeroed)
  constexpr size_t ZERO_BYTES = 65804;
  constexpr size_t OFF_LIST = 65856;                   // int[8192]
  constexpr size_t OFF_AHS  = 98688;                   // fp8 slab 8 MiB
  constexpr size_t OFF_ATG  = OFF_AHS + (size_t)NTOK * H;
  constexpr size_t OFF_WTB  = OFF_ATG + (size_t)NTOK * H;
  constexpr size_t OFF_CBB  = OFF_WTB + (size_t)CBN * H;
  constexpr size_t OFF_PM   = OFF_CBB + (size_t)CBN * H;
  constexpr size_t OFF_PL   = OFF_PM + (size_t)NCHK * NTOK * 4;
  constexpr size_t OFF_PS   = OFF_PL + (size_t)NCHK * NTOK * 4;

  float*          csq  = (float*)(ws + OFF_CSQ);
  float*          tsq  = (float*)(ws + OFF_TSQ);
  int*            cnt  = (int*)(ws + OFF_CNT);
  int*            done = (int*)(ws + OFF_DONE);
  float*          lsum = (float*)(ws + OFF_LSUM);
  int*            tdn  = (int*)(ws + OFF_TDN);
  int*            list = (int*)(ws + OFF_LIST);
  unsigned char*  Ahs  = (unsigned char*)(ws + OFF_AHS);
  unsigned char*  Atg  = (unsigned char*)(ws + OFF_ATG);
  unsigned char*  Wtb  = (unsigned char*)(ws + OFF_WTB);
  unsigned char*  Cbb  = (unsigned char*)(ws + OFF_CBB);
  float*          pm   = (float*)(ws + OFF_PM);
  float*          pl   = (float*)(ws + OFF_PL);
  float*          ps   = (float*)(ws + OFF_PS);

  hipMemsetAsync(ws, 0, ZERO_BYTES, stream);

  k_compact<<<32, 256, 0, stream>>>(ids, list, cnt);
  k_prep_all<<<4096, 256, 0, stream>>>(hs, tg, cb, W, list, cnt, csq, tsq,
                                       Wtb, Cbb, Ahs, Atg);
  k_dual<<<dim3(32, 64), 512, 0, stream>>>(Atg, Cbb, Ahs, Wtb, csq, bias, cnt,
                                           tsq, pm, pl, ps, tdn, done,
                                           lsum, (float*)d_out);
}